// Round 2
// baseline (407.769 us; speedup 1.0000x reference)
//
#include <hip/hip_runtime.h>

#define MT 16384   // B*T = 8*2048
#define NT 2048    // OUT
#define KT 2048    // IN
#define BM 128
#define BN 128
#define BK 32

typedef __attribute__((ext_vector_type(8))) short short8;     // 8 bf16 (4 VGPRs) MFMA A/B frag
typedef __attribute__((ext_vector_type(4))) float f32x4;      // MFMA C/D frag
typedef __attribute__((ext_vector_type(8))) unsigned short ushort8;
typedef __attribute__((ext_vector_type(4))) unsigned short ushort4v;

__device__ __forceinline__ unsigned short f32_bf16(float f) {
    union { float f; unsigned u; } v; v.f = f;
    // round-to-nearest-even; inputs are finite (no NaN handling needed)
    return (unsigned short)((v.u + 0x7FFFu + ((v.u >> 16) & 1u)) >> 16);
}

// ---- preconvert kernels (fast path, needs 75.5 MB workspace) ----

__global__ __launch_bounds__(256) void cvt_x_kernel(const float* __restrict__ x,
                                                    unsigned short* __restrict__ xb) {
    size_t i = ((size_t)blockIdx.x * 256 + threadIdx.x) * 8;
    float4 v0 = *(const float4*)(x + i);
    float4 v1 = *(const float4*)(x + i + 4);
    ushort8 o;
    o[0] = f32_bf16(v0.x); o[1] = f32_bf16(v0.y); o[2] = f32_bf16(v0.z); o[3] = f32_bf16(v0.w);
    o[4] = f32_bf16(v1.x); o[5] = f32_bf16(v1.y); o[6] = f32_bf16(v1.z); o[7] = f32_bf16(v1.w);
    *(ushort8*)(xb + i) = o;
}

__global__ __launch_bounds__(256) void cvt_w_kernel(const int* __restrict__ w,
                                                    unsigned short* __restrict__ wb) {
    size_t i = ((size_t)blockIdx.x * 256 + threadIdx.x) * 8;
    int4 v0 = *(const int4*)(w + i);
    int4 v1 = *(const int4*)(w + i + 4);
    ushort8 o;
    o[0] = f32_bf16((float)v0.x); o[1] = f32_bf16((float)v0.y);
    o[2] = f32_bf16((float)v0.z); o[3] = f32_bf16((float)v0.w);
    o[4] = f32_bf16((float)v1.x); o[5] = f32_bf16((float)v1.y);
    o[6] = f32_bf16((float)v1.z); o[7] = f32_bf16((float)v1.w);
    *(ushort8*)(wb + i) = o;
}

// ---- GEMM: C[m][n] = sum_k A[m][k] * W[n][k], epilogue *2^s_exp[n] + bias[n] ----
// PRE=true : A/B already bf16 in workspace -> global_load_lds width-16 staging (m97 path)
// PRE=false: fused conversion staging (fp32 x, int32 w) via VGPR round-trip

template <bool PRE>
__global__ __launch_bounds__(256) void gemm_bt(
    const unsigned short* __restrict__ Abf, const unsigned short* __restrict__ Bbf,
    const float* __restrict__ Af32, const int* __restrict__ Wi32,
    const int* __restrict__ sexp, const float* __restrict__ bias,
    float* __restrict__ C)
{
    __shared__ unsigned short As[BM * BK];   // 8 KB, row-major [128][32] bf16
    __shared__ unsigned short Bs[BN * BK];   // 8 KB

    const int tid  = threadIdx.x;
    const int row0 = blockIdx.x * BM;   // M block (fastest dim -> B tile stays L2-hot)
    const int col0 = blockIdx.y * BN;   // N block
    const int lane = tid & 63;
    const int wave = tid >> 6;
    const int wm = wave >> 1, wn = wave & 1;   // 2x2 waves, each 64x64
    const int q = lane >> 4, r = lane & 15;

    f32x4 acc[4][4] = {};

    for (int k0 = 0; k0 < KT; k0 += BK) {
        if constexpr (PRE) {
            // 8192 B per tile = 512 x 16B segments; thread covers segs tid, tid+256.
            // LDS dest is wave-uniform base + lane*16 (global_load_lds semantics).
            #pragma unroll
            for (int ii = 0; ii < 2; ++ii) {
                const int s = tid + ii * 256;               // seg: row = s>>2, chunk = s&3
                const unsigned short* ga =
                    Abf + (size_t)(row0 + (s >> 2)) * KT + k0 + (s & 3) * 8;
                __builtin_amdgcn_global_load_lds(
                    (const __attribute__((address_space(1))) unsigned int*)ga,
                    (__attribute__((address_space(3))) unsigned int*)(As + (size_t)(ii * 256 + wave * 64) * 8),
                    16, 0, 0);
                const unsigned short* gb =
                    Bbf + (size_t)(col0 + (s >> 2)) * KT + k0 + (s & 3) * 8;
                __builtin_amdgcn_global_load_lds(
                    (const __attribute__((address_space(1))) unsigned int*)gb,
                    (__attribute__((address_space(3))) unsigned int*)(Bs + (size_t)(ii * 256 + wave * 64) * 8),
                    16, 0, 0);
            }
        } else {
            // fused: 1024 float4/int4 segs per tile; thread covers 4 segs each of A and W
            #pragma unroll
            for (int ii = 0; ii < 4; ++ii) {
                const int s  = tid + ii * 256;              // row = s>>3, chunk4 = s&7
                const int rw = s >> 3, c4 = s & 7;
                float4 v = *(const float4*)(Af32 + (size_t)(row0 + rw) * KT + k0 + c4 * 4);
                ushort4v oa;
                oa[0] = f32_bf16(v.x); oa[1] = f32_bf16(v.y);
                oa[2] = f32_bf16(v.z); oa[3] = f32_bf16(v.w);
                *(ushort4v*)(As + rw * BK + c4 * 4) = oa;
                int4 w4 = *(const int4*)(Wi32 + (size_t)(col0 + rw) * KT + k0 + c4 * 4);
                ushort4v ob;
                ob[0] = f32_bf16((float)w4.x); ob[1] = f32_bf16((float)w4.y);
                ob[2] = f32_bf16((float)w4.z); ob[3] = f32_bf16((float)w4.w);
                *(ushort4v*)(Bs + rw * BK + c4 * 4) = ob;
            }
        }
        __syncthreads();   // compiler emits s_waitcnt vmcnt(0) lgkmcnt(0) before s_barrier

        // fragment loads: element j = tile[row = 16*i + r][k = q*8 + j]  (ds_read_b128)
        const unsigned short* Ab = As + (size_t)(wm * 64 + r) * BK + q * 8;
        const unsigned short* Bb = Bs + (size_t)(wn * 64 + r) * BK + q * 8;
        short8 a[4], b[4];
        #pragma unroll
        for (int i = 0; i < 4; ++i) a[i] = *(const short8*)(Ab + i * 16 * BK);
        #pragma unroll
        for (int j = 0; j < 4; ++j) b[j] = *(const short8*)(Bb + j * 16 * BK);
        #pragma unroll
        for (int i = 0; i < 4; ++i)
            #pragma unroll
            for (int j = 0; j < 4; ++j)
                acc[i][j] = __builtin_amdgcn_mfma_f32_16x16x32_bf16(a[i], b[j], acc[i][j], 0, 0, 0);
        __syncthreads();
    }

    // epilogue: C/D layout col = lane&15, row = (lane>>4)*4 + reg  [m89/m91-verified]
    #pragma unroll
    for (int j = 0; j < 4; ++j) {
        const int n  = col0 + wn * 64 + j * 16 + r;
        const float sc = ldexpf(1.0f, sexp[n]);   // exact power-of-two scale
        const float bs = bias[n];
        #pragma unroll
        for (int i = 0; i < 4; ++i) {
            const int m = row0 + wm * 64 + i * 16 + q * 4;
            float* cp = C + (size_t)m * NT + n;
            #pragma unroll
            for (int t = 0; t < 4; ++t)
                cp[(size_t)t * NT] = acc[i][j][t] * sc + bs;
        }
    }
}

extern "C" void kernel_launch(void* const* d_in, const int* in_sizes, int n_in,
                              void* d_out, int out_size, void* d_ws, size_t ws_size,
                              hipStream_t stream) {
    const float* x    = (const float*)d_in[0];
    const int*   wq   = (const int*)d_in[1];   // ternary {-1,0,1}, int32 per harness
    const int*   se   = (const int*)d_in[2];   // exponents [-8,0]
    const float* bias = (const float*)d_in[3];
    float* out = (float*)d_out;

    const size_t xb_elems = (size_t)MT * KT;   // 33554432
    const size_t wb_elems = (size_t)NT * KT;   // 4194304
    dim3 grid(MT / BM, NT / BN);               // (128, 16)

    if (ws_size >= (xb_elems + wb_elems) * sizeof(unsigned short)) {
        unsigned short* xb = (unsigned short*)d_ws;
        unsigned short* wb = xb + xb_elems;
        cvt_x_kernel<<<(int)(xb_elems / (256 * 8)), 256, 0, stream>>>(x, xb);
        cvt_w_kernel<<<(int)(wb_elems / (256 * 8)), 256, 0, stream>>>(wq, wb);
        gemm_bt<true><<<grid, 256, 0, stream>>>(xb, wb, nullptr, nullptr, se, bias, out);
    } else {
        gemm_bt<false><<<grid, 256, 0, stream>>>(nullptr, nullptr, x, wq, se, bias, out);
    }
}

// Round 3
// 403.971 us; speedup vs baseline: 1.0094x; 1.0094x over previous
//
#include <hip/hip_runtime.h>

#define MT 16384   // B*T = 8*2048
#define NT 2048    // OUT
#define KT 2048    // IN
#define BM 128
#define BN 128
#define BK 32

typedef __attribute__((ext_vector_type(8))) short short8;     // 8 bf16 (4 VGPRs) MFMA A/B frag
typedef __attribute__((ext_vector_type(4))) float f32x4;      // MFMA C/D frag
typedef __attribute__((ext_vector_type(8))) unsigned short ushort8;
typedef __attribute__((ext_vector_type(4))) unsigned short ushort4v;

__device__ __forceinline__ unsigned short f32_bf16(float f) {
    union { float f; unsigned u; } v; v.f = f;
    return (unsigned short)((v.u + 0x7FFFu + ((v.u >> 16) & 1u)) >> 16);
}

// ---- merged preconvert: x (fp32->bf16) then w (int32->bf16), one dispatch ----
// x part: 16384 blocks * 2048 elems; w part: 2048 blocks.

__global__ __launch_bounds__(256) void cvt_kernel(const float* __restrict__ x,
                                                  const int* __restrict__ w,
                                                  unsigned short* __restrict__ xb,
                                                  unsigned short* __restrict__ wb) {
    const int b = blockIdx.x;
    if (b < MT * KT / 2048) {
        size_t i = ((size_t)b * 256 + threadIdx.x) * 8;
        float4 v0 = *(const float4*)(x + i);
        float4 v1 = *(const float4*)(x + i + 4);
        ushort8 o;
        o[0] = f32_bf16(v0.x); o[1] = f32_bf16(v0.y); o[2] = f32_bf16(v0.z); o[3] = f32_bf16(v0.w);
        o[4] = f32_bf16(v1.x); o[5] = f32_bf16(v1.y); o[6] = f32_bf16(v1.z); o[7] = f32_bf16(v1.w);
        *(ushort8*)(xb + i) = o;
    } else {
        size_t i = ((size_t)(b - MT * KT / 2048) * 256 + threadIdx.x) * 8;
        int4 v0 = *(const int4*)(w + i);
        int4 v1 = *(const int4*)(w + i + 4);
        ushort8 o;
        o[0] = f32_bf16((float)v0.x); o[1] = f32_bf16((float)v0.y);
        o[2] = f32_bf16((float)v0.z); o[3] = f32_bf16((float)v0.w);
        o[4] = f32_bf16((float)v1.x); o[5] = f32_bf16((float)v1.y);
        o[6] = f32_bf16((float)v1.z); o[7] = f32_bf16((float)v1.w);
        *(ushort8*)(wb + i) = o;
    }
}

// ---- GEMM: C[m][n] = sum_k A[m][k] * W[n][k], epilogue *2^s_exp[n] + bias[n] ----
// LDS tiles are stored with a 16B-chunk swizzle to kill ds_read_b128 bank
// conflicts: logical (row, chunk q in [0,4)) lives at slot row*4 + ((q + (row>>1))&3).
// R2 evidence: un-swizzled layout -> SQ_LDS_BANK_CONFLICT = 1.678e7 (8-way on
// every frag read: 16 lanes/q-group land in one 4-bank group per row parity).
// Swizzle costs nothing: global_load_lds dest is base+lane*16, so we permute
// the GLOBAL source address per lane instead of the LDS destination.

__device__ __forceinline__ int swz(int row, int q) {        // logical chunk -> slot
    return row * 4 + ((q + (row >> 1)) & 3);
}

template <bool PRE>
__global__ __launch_bounds__(256) void gemm_bt(
    const unsigned short* __restrict__ Abf, const unsigned short* __restrict__ Bbf,
    const float* __restrict__ Af32, const int* __restrict__ Wi32,
    const int* __restrict__ sexp, const float* __restrict__ bias,
    float* __restrict__ C)
{
    __shared__ unsigned short As[BM * BK];   // 8 KB, swizzled [128][4 chunks of 8 bf16]
    __shared__ unsigned short Bs[BN * BK];   // 8 KB

    const int tid  = threadIdx.x;
    const int row0 = blockIdx.x * BM;   // M block
    const int col0 = blockIdx.y * BN;   // N block
    const int lane = tid & 63;
    const int wave = tid >> 6;
    const int wm = wave >> 1, wn = wave & 1;   // 2x2 waves, each 64x64
    const int q = lane >> 4, r = lane & 15;

    f32x4 acc[4][4] = {};

    for (int k0 = 0; k0 < KT; k0 += BK) {
        if constexpr (PRE) {
            // 512 x 16B slots per tile; slot s holds logical chunk (s&3)-(row>>1) mod 4
            // of row s>>2 -> after HW's base+lane*16 placement, LDS slot s = swz(row, q).
            #pragma unroll
            for (int ii = 0; ii < 2; ++ii) {
                const int s   = tid + ii * 256;
                const int row = s >> 2;
                const int cg  = ((s & 3) - (row >> 1)) & 3;   // logical chunk stored here
                const unsigned short* ga =
                    Abf + (size_t)(row0 + row) * KT + k0 + cg * 8;
                __builtin_amdgcn_global_load_lds(
                    (const __attribute__((address_space(1))) unsigned int*)ga,
                    (__attribute__((address_space(3))) unsigned int*)(As + (size_t)(ii * 256 + wave * 64) * 8),
                    16, 0, 0);
                const unsigned short* gb =
                    Bbf + (size_t)(col0 + row) * KT + k0 + cg * 8;
                __builtin_amdgcn_global_load_lds(
                    (const __attribute__((address_space(1))) unsigned int*)gb,
                    (__attribute__((address_space(3))) unsigned int*)(Bs + (size_t)(ii * 256 + wave * 64) * 8),
                    16, 0, 0);
            }
        } else {
            // fused fallback: write the same swizzled layout (8B granules)
            #pragma unroll
            for (int ii = 0; ii < 4; ++ii) {
                const int s  = tid + ii * 256;
                const int rw = s >> 3, c4 = s & 7;            // c4: 8B granule in row
                const int ch = c4 >> 1, hf = c4 & 1;          // logical 16B chunk + half
                const int ps = ((ch + (rw >> 1)) & 3) * 8 + hf * 4;  // swizzled short offset
                float4 v = *(const float4*)(Af32 + (size_t)(row0 + rw) * KT + k0 + c4 * 4);
                ushort4v oa;
                oa[0] = f32_bf16(v.x); oa[1] = f32_bf16(v.y);
                oa[2] = f32_bf16(v.z); oa[3] = f32_bf16(v.w);
                *(ushort4v*)(As + rw * BK + ps) = oa;
                int4 w4 = *(const int4*)(Wi32 + (size_t)(col0 + rw) * KT + k0 + c4 * 4);
                ushort4v ob;
                ob[0] = f32_bf16((float)w4.x); ob[1] = f32_bf16((float)w4.y);
                ob[2] = f32_bf16((float)w4.z); ob[3] = f32_bf16((float)w4.w);
                *(ushort4v*)(Bs + rw * BK + ps) = ob;
            }
        }
        __syncthreads();

        // fragment loads: element j = tile[row = 16*i + r][k = q*8 + j], via swizzled slot
        short8 a[4], b[4];
        #pragma unroll
        for (int i = 0; i < 4; ++i)
            a[i] = *(const short8*)(As + swz(wm * 64 + i * 16 + r, q) * 8);
        #pragma unroll
        for (int j = 0; j < 4; ++j)
            b[j] = *(const short8*)(Bs + swz(wn * 64 + j * 16 + r, q) * 8);
        #pragma unroll
        for (int i = 0; i < 4; ++i)
            #pragma unroll
            for (int j = 0; j < 4; ++j)
                acc[i][j] = __builtin_amdgcn_mfma_f32_16x16x32_bf16(a[i], b[j], acc[i][j], 0, 0, 0);
        __syncthreads();
    }

    // epilogue: C/D layout col = lane&15, row = (lane>>4)*4 + reg  [m89/m91-verified]
    #pragma unroll
    for (int j = 0; j < 4; ++j) {
        const int n  = col0 + wn * 64 + j * 16 + r;
        const float sc = ldexpf(1.0f, sexp[n]);   // exact power-of-two scale
        const float bs = bias[n];
        #pragma unroll
        for (int i = 0; i < 4; ++i) {
            const int m = row0 + wm * 64 + i * 16 + q * 4;
            float* cp = C + (size_t)m * NT + n;
            #pragma unroll
            for (int t = 0; t < 4; ++t)
                cp[(size_t)t * NT] = acc[i][j][t] * sc + bs;
        }
    }
}

extern "C" void kernel_launch(void* const* d_in, const int* in_sizes, int n_in,
                              void* d_out, int out_size, void* d_ws, size_t ws_size,
                              hipStream_t stream) {
    const float* x    = (const float*)d_in[0];
    const int*   wq   = (const int*)d_in[1];   // ternary {-1,0,1}, int32 per harness
    const int*   se   = (const int*)d_in[2];   // exponents [-8,0]
    const float* bias = (const float*)d_in[3];
    float* out = (float*)d_out;

    const size_t xb_elems = (size_t)MT * KT;   // 33554432
    const size_t wb_elems = (size_t)NT * KT;   // 4194304
    dim3 grid(MT / BM, NT / BN);               // (128, 16)

    if (ws_size >= (xb_elems + wb_elems) * sizeof(unsigned short)) {
        unsigned short* xb = (unsigned short*)d_ws;
        unsigned short* wb = xb + xb_elems;
        cvt_kernel<<<(int)((xb_elems + wb_elems) / (256 * 8)), 256, 0, stream>>>(x, wq, xb, wb);
        gemm_bt<true><<<grid, 256, 0, stream>>>(xb, wb, nullptr, nullptr, se, bias, out);
    } else {
        gemm_bt<false><<<grid, 256, 0, stream>>>(nullptr, nullptr, x, wq, se, bias, out);
    }
}

// Round 4
// 399.032 us; speedup vs baseline: 1.0219x; 1.0124x over previous
//
#include <hip/hip_runtime.h>

#define MT 16384   // B*T = 8*2048
#define NT 2048    // OUT
#define KT 2048    // IN
#define BM 128
#define BN 128
#define BK 64      // R3->R4: 32->64. Halves barrier pairs (the exposed per-iter
                   // vmcnt(0) drain); LDS 16->32 KB keeps ~3 blocks/CU (m132's
                   // BK=128/64KB regression does not apply at 32 KB).

typedef __attribute__((ext_vector_type(8))) short short8;     // 8 bf16 (4 VGPRs) MFMA A/B frag
typedef __attribute__((ext_vector_type(4))) float f32x4;      // MFMA C/D frag
typedef __attribute__((ext_vector_type(8))) unsigned short ushort8;
typedef __attribute__((ext_vector_type(4))) unsigned short ushort4v;

__device__ __forceinline__ unsigned short f32_bf16(float f) {
    union { float f; unsigned u; } v; v.f = f;
    return (unsigned short)((v.u + 0x7FFFu + ((v.u >> 16) & 1u)) >> 16);
}

// ---- merged preconvert: x (fp32->bf16) then w (int32->bf16), one dispatch ----

__global__ __launch_bounds__(256) void cvt_kernel(const float* __restrict__ x,
                                                  const int* __restrict__ w,
                                                  unsigned short* __restrict__ xb,
                                                  unsigned short* __restrict__ wb) {
    const int b = blockIdx.x;
    if (b < MT * KT / 2048) {
        size_t i = ((size_t)b * 256 + threadIdx.x) * 8;
        float4 v0 = *(const float4*)(x + i);
        float4 v1 = *(const float4*)(x + i + 4);
        ushort8 o;
        o[0] = f32_bf16(v0.x); o[1] = f32_bf16(v0.y); o[2] = f32_bf16(v0.z); o[3] = f32_bf16(v0.w);
        o[4] = f32_bf16(v1.x); o[5] = f32_bf16(v1.y); o[6] = f32_bf16(v1.z); o[7] = f32_bf16(v1.w);
        *(ushort8*)(xb + i) = o;
    } else {
        size_t i = ((size_t)(b - MT * KT / 2048) * 256 + threadIdx.x) * 8;
        int4 v0 = *(const int4*)(w + i);
        int4 v1 = *(const int4*)(w + i + 4);
        ushort8 o;
        o[0] = f32_bf16((float)v0.x); o[1] = f32_bf16((float)v0.y);
        o[2] = f32_bf16((float)v0.z); o[3] = f32_bf16((float)v0.w);
        o[4] = f32_bf16((float)v1.x); o[5] = f32_bf16((float)v1.y);
        o[6] = f32_bf16((float)v1.z); o[7] = f32_bf16((float)v1.w);
        *(ushort8*)(wb + i) = o;
    }
}

// ---- GEMM: C[m][n] = sum_k A[m][k] * W[n][k], epilogue *2^s_exp[n] + bias[n] ----
// LDS layout: row-major [128][8 chunks of 16B], chunk swizzled:
//   logical (row, chunk c in [0,8)) lives at slot row*8 + ((c + row) & 7).
// R3 verified the swizzle principle (SQ_LDS_BANK_CONFLICT 1.678e7 -> 0); this is
// the 8-chunk generalization. Frag reads hit each 4-bank group with exactly 8
// lanes = the 1024B/128B structural floor for wave-b128. Swizzle is free: we
// permute the GLOBAL source per lane; global_load_lds dest stays base+lane*16.

__device__ __forceinline__ int swz(int row, int c) {        // logical chunk -> slot
    return row * 8 + ((c + row) & 7);
}

template <bool PRE>
__global__ __launch_bounds__(256) void gemm_bt(
    const unsigned short* __restrict__ Abf, const unsigned short* __restrict__ Bbf,
    const float* __restrict__ Af32, const int* __restrict__ Wi32,
    const int* __restrict__ sexp, const float* __restrict__ bias,
    float* __restrict__ C)
{
    __shared__ unsigned short As[BM * BK];   // 16 KB
    __shared__ unsigned short Bs[BN * BK];   // 16 KB

    const int tid  = threadIdx.x;
    const int row0 = blockIdx.x * BM;   // M block
    const int col0 = blockIdx.y * BN;   // N block
    const int lane = tid & 63;
    const int wave = tid >> 6;
    const int wm = wave >> 1, wn = wave & 1;   // 2x2 waves, each 64x64
    const int q = lane >> 4, r = lane & 15;

    f32x4 acc[4][4] = {};

    for (int k0 = 0; k0 < KT; k0 += BK) {
        if constexpr (PRE) {
            // 1024 x 16B slots per matrix; slot s=(row, pos) holds logical chunk
            // (pos - row) & 7 of row s>>3. 256 threads x 4 iters cover it.
            #pragma unroll
            for (int ii = 0; ii < 4; ++ii) {
                const int s   = tid + ii * 256;
                const int row = s >> 3;
                const int cg  = ((s & 7) - row) & 7;          // logical chunk stored here
                const unsigned short* ga =
                    Abf + (size_t)(row0 + row) * KT + k0 + cg * 8;
                __builtin_amdgcn_global_load_lds(
                    (const __attribute__((address_space(1))) unsigned int*)ga,
                    (__attribute__((address_space(3))) unsigned int*)(As + (size_t)(ii * 256 + wave * 64) * 8),
                    16, 0, 0);
                const unsigned short* gb =
                    Bbf + (size_t)(col0 + row) * KT + k0 + cg * 8;
                __builtin_amdgcn_global_load_lds(
                    (const __attribute__((address_space(1))) unsigned int*)gb,
                    (__attribute__((address_space(3))) unsigned int*)(Bs + (size_t)(ii * 256 + wave * 64) * 8),
                    16, 0, 0);
            }
        } else {
            // fused fallback: same swizzled layout, 8B granules (16 per row)
            #pragma unroll
            for (int ii = 0; ii < 8; ++ii) {
                const int s  = tid + ii * 256;
                const int rw = s >> 4, c4 = s & 15;           // 8B granule in row
                const int ch = c4 >> 1, hf = c4 & 1;          // logical 16B chunk + half
                const int ps = ((ch + rw) & 7) * 8 + hf * 4;  // swizzled short offset
                float4 v = *(const float4*)(Af32 + (size_t)(row0 + rw) * KT + k0 + c4 * 4);
                ushort4v oa;
                oa[0] = f32_bf16(v.x); oa[1] = f32_bf16(v.y);
                oa[2] = f32_bf16(v.z); oa[3] = f32_bf16(v.w);
                *(ushort4v*)(As + rw * BK + ps) = oa;
                int4 w4 = *(const int4*)(Wi32 + (size_t)(col0 + rw) * KT + k0 + c4 * 4);
                ushort4v ob;
                ob[0] = f32_bf16((float)w4.x); ob[1] = f32_bf16((float)w4.y);
                ob[2] = f32_bf16((float)w4.z); ob[3] = f32_bf16((float)w4.w);
                *(ushort4v*)(Bs + rw * BK + ps) = ob;
            }
        }
        __syncthreads();

        // two K=32 halves; frag element j = tile[row][k = h*32 + q*8 + j]
        // logical chunk c = h*4 + q  ->  slot via swz(row, c)
        #pragma unroll
        for (int h = 0; h < 2; ++h) {
            short8 a[4], b[4];
            #pragma unroll
            for (int i = 0; i < 4; ++i)
                a[i] = *(const short8*)(As + swz(wm * 64 + i * 16 + r, h * 4 + q) * 8);
            #pragma unroll
            for (int j = 0; j < 4; ++j)
                b[j] = *(const short8*)(Bs + swz(wn * 64 + j * 16 + r, h * 4 + q) * 8);
            #pragma unroll
            for (int i = 0; i < 4; ++i)
                #pragma unroll
                for (int j = 0; j < 4; ++j)
                    acc[i][j] = __builtin_amdgcn_mfma_f32_16x16x32_bf16(a[i], b[j], acc[i][j], 0, 0, 0);
        }
        __syncthreads();
    }

    // epilogue: C/D layout col = lane&15, row = (lane>>4)*4 + reg  [m89/m91-verified]
    #pragma unroll
    for (int j = 0; j < 4; ++j) {
        const int n  = col0 + wn * 64 + j * 16 + r;
        const float sc = ldexpf(1.0f, sexp[n]);   // exact power-of-two scale
        const float bs = bias[n];
        #pragma unroll
        for (int i = 0; i < 4; ++i) {
            const int m = row0 + wm * 64 + i * 16 + q * 4;
            float* cp = C + (size_t)m * NT + n;
            #pragma unroll
            for (int t = 0; t < 4; ++t)
                cp[(size_t)t * NT] = acc[i][j][t] * sc + bs;
        }
    }
}

extern "C" void kernel_launch(void* const* d_in, const int* in_sizes, int n_in,
                              void* d_out, int out_size, void* d_ws, size_t ws_size,
                              hipStream_t stream) {
    const float* x    = (const float*)d_in[0];
    const int*   wq   = (const int*)d_in[1];   // ternary {-1,0,1}, int32 per harness
    const int*   se   = (const int*)d_in[2];   // exponents [-8,0]
    const float* bias = (const float*)d_in[3];
    float* out = (float*)d_out;

    const size_t xb_elems = (size_t)MT * KT;   // 33554432
    const size_t wb_elems = (size_t)NT * KT;   // 4194304
    dim3 grid(MT / BM, NT / BN);               // (128, 16)

    if (ws_size >= (xb_elems + wb_elems) * sizeof(unsigned short)) {
        unsigned short* xb = (unsigned short*)d_ws;
        unsigned short* wb = xb + xb_elems;
        cvt_kernel<<<(int)((xb_elems + wb_elems) / (256 * 8)), 256, 0, stream>>>(x, wq, xb, wb);
        gemm_bt<true><<<grid, 256, 0, stream>>>(xb, wb, nullptr, nullptr, se, bias, out);
    } else {
        gemm_bt<false><<<grid, 256, 0, stream>>>(nullptr, nullptr, x, wq, se, bias, out);
    }
}